// Round 9
// baseline (686.778 us; speedup 1.0000x reference)
//
#include <hip/hip_runtime.h>
#include <stdint.h>

// ---------------------------------------------------------------------------
// GaussianVectorQuantizer (training) MI355X.
// Outputs (flat f32): zq[2097152] | precision_q[1] | prob[4194304] | log_prob[4194304]
// RNG (verified R2): threefry2x32 partitionable, fold-like split, draw = o0^o1.
// R9: k_zq = LDS-staged (R4-style) x shuffle P-exchange (R7) x S^T orientation,
//     256-thr blocks + launch_bounds(256,3) targeting 3 waves/SIMD.
// ---------------------------------------------------------------------------

typedef __attribute__((ext_vector_type(8))) __bf16 bf16x8;
typedef __attribute__((ext_vector_type(4))) float f32x4;

// ws float-offsets
#define F_CP     0
#define F_BK2    512
#define F_AS     5632
#define F_ASUM   10752
#define F_LSE    27136
#define O_BKRM   190976u
#define O_BKT    846336u
#define O_MH     1501696u
#define O_PART   1501696u   // overlays Mh (k_zq runs after k_probs)

__device__ __forceinline__ uint32_t rotl32(uint32_t x, int r){ return (x << r) | (x >> (32 - r)); }

__device__ __forceinline__ void tf2x32(uint32_t k0, uint32_t k1, uint32_t x0, uint32_t x1,
                                       uint32_t &o0, uint32_t &o1){
  uint32_t k2 = k0 ^ k1 ^ 0x1BD11BDAu;
  x0 += k0; x1 += k1;
#define TFR(r) { x0 += x1; x1 = rotl32(x1,(r)); x1 ^= x0; }
  TFR(13) TFR(15) TFR(26) TFR(6)
  x0 += k1; x1 += k2 + 1u;
  TFR(17) TFR(29) TFR(16) TFR(24)
  x0 += k2; x1 += k0 + 2u;
  TFR(13) TFR(15) TFR(26) TFR(6)
  x0 += k0; x1 += k1 + 3u;
  TFR(17) TFR(29) TFR(16) TFR(24)
  x0 += k1; x1 += k2 + 4u;
  TFR(13) TFR(15) TFR(26) TFR(6)
  x0 += k2; x1 += k0 + 5u;
#undef TFR
  o0 = x0; o1 = x1;
}

__device__ __forceinline__ uint32_t rbits0(uint32_t k0, uint32_t k1, uint32_t i){
  uint32_t o0, o1; tf2x32(k0, k1, 0u, i, o0, o1); return o0 ^ o1;
}
__device__ __forceinline__ float bits_to_u01(uint32_t b){
  return __uint_as_float((b >> 9) | 0x3F800000u) - 1.0f;
}
__device__ __forceinline__ float gumbel_u(float u){
  return -__logf(-__logf(u + 1e-10f) + 1e-10f);
}
__device__ __forceinline__ float gum_at(uint32_t k0, uint32_t k1, uint32_t idx){
  return gumbel_u(bits_to_u01(rbits0(k0, k1, idx)));
}
__device__ __forceinline__ uint16_t bfbits(float x){
  union { __bf16 h; uint16_t s; } u; u.h = (__bf16)x; return u.s;
}
__device__ __forceinline__ uint32_t pk2(float a, float b){
  return (uint32_t)bfbits(a) | ((uint32_t)bfbits(b) << 16);
}
__device__ __forceinline__ float bflo(uint32_t u){ return __uint_as_float((u & 0xFFFFu) << 16); }
__device__ __forceinline__ float bfhi(uint32_t u){ return __uint_as_float((u >> 16) << 16); }

// ---------------------------------------------------------------------------
// k_prep: books -> bkrm bf16 + bkT bf16; bk2 + As = -2pq*bk2; cprob; precision_q.
// grid 80 = c(10) x k0(8 tiles of 64 rows), 256 threads.
// ---------------------------------------------------------------------------
__global__ void __launch_bounds__(256)
k_prep(const float* __restrict__ books, const float* __restrict__ c_logits,
       const float* __restrict__ lpq, const float* __restrict__ lpqc,
       float* __restrict__ ws, float* __restrict__ out,
       uint16_t* __restrict__ bkrm, uint16_t* __restrict__ bkTg){
  __shared__ __align__(16) char tsm[32768];   // [64][256] bf16, swizzled
  int c = blockIdx.x >> 3, k0 = (blockIdx.x & 7) << 6;
  int t = threadIdx.x, lane = t & 63, w4 = t >> 6;
  float pq = 0.5f / fmaxf(1.0f + __expf(lpq[0]), 1e-10f);
  #pragma unroll
  for (int q = 0; q < 16; ++q){
    int kk = q * 4 + w4, d = lane * 4;
    float4 v = *(const float4*)(books + ((size_t)(c*512 + k0 + kk))*256 + d);
    float s = v.x*v.x + v.y*v.y + v.z*v.z + v.w*v.w;
    #pragma unroll
    for (int m = 1; m < 64; m <<= 1) s += __shfl_xor(s, m);
    if (lane == 0){
      ws[F_BK2 + c*512 + k0 + kk] = s;
      ws[F_AS  + c*512 + k0 + kk] = -2.0f * pq * s;
    }
    uint2 h; h.x = pk2(v.x, v.y); h.y = pk2(v.z, v.w);
    *(uint2*)(bkrm + ((size_t)(c*512 + k0 + kk))*256 + d) = h;
    int base = (kk << 9) + (d << 1);
    *(uint2*)(tsm + (base ^ ((kk & 7) << 4))) = h;
  }
  __syncthreads();
  {
    int d = t;
    uint16_t tmp[64];
    #pragma unroll
    for (int kk = 0; kk < 64; ++kk)
      tmp[kk] = *(uint16_t*)(tsm + (((kk << 9) + (d << 1)) ^ ((kk & 7) << 4)));
    #pragma unroll
    for (int q = 0; q < 8; ++q)
      *(uint4*)(bkTg + ((size_t)(c*256 + d))*512 + k0 + q*8) = *(uint4*)&tmp[q*8];
  }
  if (blockIdx.x == 0){
    if (t == 0) out[2097152] = pq;
    if (t < 32){
      int b = t;
      float pqc = 0.5f / fmaxf(1.0f + __expf(lpqc[0]), 1e-10f);
      uint32_t kc0, kc1; tf2x32(0u, 42u, 0u, 0u, kc0, kc1);
      float y[10]; float mx = -1e30f;
      #pragma unroll
      for (int c2 = 0; c2 < 10; ++c2){
        float g = gum_at(kc0, kc1, (uint32_t)(b * 10 + c2));
        float v = (c_logits[b * 10 + c2] * pqc + g) * 2.0f;
        y[c2] = v; mx = fmaxf(mx, v);
      }
      float s = 0.f;
      #pragma unroll
      for (int c2 = 0; c2 < 10; ++c2){ y[c2] = __expf(y[c2] - mx); s += y[c2]; }
      float inv = 1.0f / s;
      #pragma unroll
      for (int c2 = 0; c2 < 10; ++c2) ws[F_CP + b * 10 + c2] = y[c2] * inv;
    }
  }
}

// ---------------------------------------------------------------------------
// k_mix: Mh[b][k][d] = sum_c cp*bkrm  (bf16);  Asum[b][k] = -pq*sum_c cp*bk2.
// grid 4096 = b(32) x kgroup(128 of 4 rows), 256 threads.
// ---------------------------------------------------------------------------
__global__ void __launch_bounds__(256)
k_mix(const uint16_t* __restrict__ bkrm, const float* __restrict__ lpq,
      float* __restrict__ ws, uint16_t* __restrict__ Mh){
  int blk = blockIdx.x;
  int b = blk >> 7, kg = blk & 127;
  int t = threadIdx.x, kr = t >> 6, lane = t & 63;
  int k = kg * 4 + kr, d = lane * 4;
  float a0=0.f, a1=0.f, a2=0.f, a3=0.f;
  float cp[10];
  #pragma unroll
  for (int c = 0; c < 10; ++c) cp[c] = ws[F_CP + b*10 + c];
  #pragma unroll
  for (int c = 0; c < 10; ++c){
    uint2 v = *(const uint2*)(bkrm + ((size_t)(c*512 + k))*256 + d);
    a0 = fmaf(cp[c], bflo(v.x), a0); a1 = fmaf(cp[c], bfhi(v.x), a1);
    a2 = fmaf(cp[c], bflo(v.y), a2); a3 = fmaf(cp[c], bfhi(v.y), a3);
  }
  uint2 h; h.x = pk2(a0, a1); h.y = pk2(a2, a3);
  *(uint2*)(Mh + ((size_t)(b*512 + k))*256 + d) = h;
  if (lane == 0){
    float pq = 0.5f / fmaxf(1.0f + __expf(lpq[0]), 1e-10f);
    float s = 0.f;
    #pragma unroll
    for (int c = 0; c < 10; ++c) s = fmaf(cp[c], ws[F_BK2 + c*512 + k], s);
    ws[F_ASUM + b*512 + k] = -pq * s;
  }
}

// ---------------------------------------------------------------------------
// k_probs_mf: prob/log_prob via MFMA, k split across 2 waves (LSE-merged).
// grid 512 x 128 thr.
// ---------------------------------------------------------------------------
__global__ void __launch_bounds__(128)
k_probs_mf(const float* __restrict__ ze, const uint16_t* __restrict__ Mh,
           const float* __restrict__ ws, const float* __restrict__ lpq,
           float* __restrict__ prob, float* __restrict__ logp){
  __shared__ float Lh[2][16];
  int b = blockIdx.x >> 4, n0 = (blockIdx.x & 15) << 4;
  int h = threadIdx.x >> 6;
  int lane = threadIdx.x & 63, g = lane >> 4, r16 = lane & 15;
  float pq = 0.5f / fmaxf(1.0f + __expf(lpq[0]), 1e-10f);
  float twopq = 2.0f * pq;

  bf16x8 za[8];
  {
    const float* zp = ze + ((size_t)(b * 256 + n0 + r16)) * 256 + g * 8;
    #pragma unroll
    for (int dt = 0; dt < 8; ++dt){
      float4 v0 = *(const float4*)(zp + dt * 32);
      float4 v1 = *(const float4*)(zp + dt * 32 + 4);
      bf16x8 z;
      z[0]=(__bf16)v0.x; z[1]=(__bf16)v0.y; z[2]=(__bf16)v0.z; z[3]=(__bf16)v0.w;
      z[4]=(__bf16)v1.x; z[5]=(__bf16)v1.y; z[6]=(__bf16)v1.z; z[7]=(__bf16)v1.w;
      za[dt] = z;
    }
  }

  f32x4 va[8], vb[8];
  float m = -1e30f, l = 0.f;
  #pragma unroll
  for (int p = 0; p < 8; ++p){
    int kabs = (h << 8) + (p << 5);
    const uint16_t* s0 = Mh + ((size_t)(b*512 + kabs + r16))*256 + g*8;
    const uint16_t* s1 = s0 + (size_t)16*256;
    f32x4 a0 = (f32x4)(0.f), a1 = (f32x4)(0.f);
    #pragma unroll
    for (int dt = 0; dt < 8; ++dt){
      bf16x8 f0 = *(const bf16x8*)(s0 + dt*32);
      bf16x8 f1 = *(const bf16x8*)(s1 + dt*32);
      a0 = __builtin_amdgcn_mfma_f32_16x16x32_bf16(f0, za[dt], a0, 0, 0, 0);
      a1 = __builtin_amdgcn_mfma_f32_16x16x32_bf16(f1, za[dt], a1, 0, 0, 0);
    }
    float4 as0 = *(const float4*)(ws + F_ASUM + b*512 + kabs + 4*g);
    float4 as1 = *(const float4*)(ws + F_ASUM + b*512 + kabs + 16 + 4*g);
    f32x4 v0, v1;
    v0[0] = fmaf(twopq, a0[0], as0.x); v0[1] = fmaf(twopq, a0[1], as0.y);
    v0[2] = fmaf(twopq, a0[2], as0.z); v0[3] = fmaf(twopq, a0[3], as0.w);
    v1[0] = fmaf(twopq, a1[0], as1.x); v1[1] = fmaf(twopq, a1[1], as1.y);
    v1[2] = fmaf(twopq, a1[2], as1.z); v1[3] = fmaf(twopq, a1[3], as1.w);
    va[p] = v0; vb[p] = v1;
    float mr = fmaxf(fmaxf(fmaxf(v0[0], v0[1]), fmaxf(v0[2], v0[3])),
                     fmaxf(fmaxf(v1[0], v1[1]), fmaxf(v1[2], v1[3])));
    mr = fmaxf(mr, __shfl_xor(mr, 16));
    mr = fmaxf(mr, __shfl_xor(mr, 32));
    float mn = fmaxf(m, mr);
    float sc = __expf(m - mn);
    float cs = 0.f;
    #pragma unroll
    for (int i = 0; i < 4; ++i) cs += __expf(v0[i] - mn);
    #pragma unroll
    for (int i = 0; i < 4; ++i) cs += __expf(v1[i] - mn);
    l = l * sc + cs;
    m = mn;
  }
  l += __shfl_xor(l, 16);
  l += __shfl_xor(l, 32);
  if (g == 0) Lh[h][r16] = m + __logf(l);
  __syncthreads();
  float L0 = Lh[0][r16], L1 = Lh[1][r16];
  float mx = fmaxf(L0, L1);
  float lse = mx + __logf(__expf(L0 - mx) + __expf(L1 - mx));
  float* pb = prob + ((size_t)(b*256 + n0 + r16))*512;
  float* lb = logp + ((size_t)(b*256 + n0 + r16))*512;
  #pragma unroll
  for (int p = 0; p < 8; ++p){
    int kabs = (h << 8) + (p << 5) + 4*g;
    f32x4 v0 = va[p], v1 = vb[p];
    float4 l0 = {v0[0]-lse, v0[1]-lse, v0[2]-lse, v0[3]-lse};
    float4 l1 = {v1[0]-lse, v1[1]-lse, v1[2]-lse, v1[3]-lse};
    float4 p0 = {__expf(l0.x), __expf(l0.y), __expf(l0.z), __expf(l0.w)};
    float4 p1 = {__expf(l1.x), __expf(l1.y), __expf(l1.z), __expf(l1.w)};
    *(float4*)(lb + kabs)      = l0;
    *(float4*)(lb + kabs + 16) = l1;
    *(float4*)(pb + kabs)      = p0;
    *(float4*)(pb + kabs + 16) = p1;
  }
}

// ---------------------------------------------------------------------------
// k_zq_st: LDS-staged flash zq. grid 2560 x 256 thr (4 waves x 16 rows).
// Block = (c slowest via XCD swizzle, b, ntile of 64 rows, khalf of 256).
// LDS 32KB: bk [32 k][32 chunk16] (chunk ^= k&7) | bkT [256 d][4 slot16]
// (slot ^= d&3). S^T QK (mfma(bk,za)); shuffle P-exchange; per-iter:
// issue global loads -> gumbels (covers latency) -> barrier -> ds_write ->
// barrier -> QK/softmax/PV.
// ---------------------------------------------------------------------------
__global__ void __launch_bounds__(256, 3)
k_zq_st(const float* __restrict__ ze, const uint16_t* __restrict__ bkrm,
        const uint16_t* __restrict__ bkTg, const float* __restrict__ ws,
        const float* __restrict__ lpq, uint16_t* __restrict__ part,
        float* __restrict__ lseg){
  __shared__ __align__(16) char sm[32768];
  int bid = blockIdx.x;
  int wg = (bid & 7) * 320 + (bid >> 3);     // bijective (2560 % 8 == 0)
  int c = wg >> 8;                           // c slowest: 256 blocks per c
  int rem = wg & 255;
  int b = rem >> 3, r2 = rem & 7, nt = r2 >> 1, h = r2 & 1;
  int tid = threadIdx.x, w = tid >> 6, lane = tid & 63, g = lane >> 4, r16 = lane & 15;
  int n0 = nt * 64 + w * 16;
  const int kb0 = h << 8;
  float pq = 0.5f / fmaxf(1.0f + __expf(lpq[0]), 1e-10f);
  float fourpq = 4.0f * pq;
  uint32_t ke0, ke1; tf2x32(0u, 42u, 0u, 1u, ke0, ke1);
  const int srcA = (g & 1) * 32 + r16;       // P-exchange source lanes
  const int srcB = srcA + 16;
  const bool selhi = (g >= 2);

  // staging source addresses (constant over iterations except kabs)
  // segs 0..15: bk rows (2 rows/seg); segs 16..31: bkT (16 d-rows/seg)
  const int seg0 = w * 8;
  bf16x8 za[8];
  {
    const float* zp = ze + ((size_t)(b * 256 + n0 + r16)) * 256 + g * 8;
    #pragma unroll
    for (int dt = 0; dt < 8; ++dt){
      float4 v0 = *(const float4*)(zp + dt * 32);
      float4 v1 = *(const float4*)(zp + dt * 32 + 4);
      bf16x8 z;
      z[0]=(__bf16)v0.x; z[1]=(__bf16)v0.y; z[2]=(__bf16)v0.z; z[3]=(__bf16)v0.w;
      z[4]=(__bf16)v1.x; z[5]=(__bf16)v1.y; z[6]=(__bf16)v1.z; z[7]=(__bf16)v1.w;
      za[dt] = z;
    }
  }

  f32x4 o[16];
  #pragma unroll
  for (int i = 0; i < 16; ++i) o[i] = (f32x4)(0.f);
  float m = -1e30f, l = 0.f;
  const uint32_t nb = ((uint32_t)((b*10 + c)*256 + n0 + r16)) << 9;

  for (int p = 0; p < 8; ++p){
    int kabs = kb0 + (p << 5);
    // ---- issue staging loads (8 x 16B/thread) ----
    uint4 st[8];
    int srow[4], schk[4], sd[4], sslot[4];
    #pragma unroll
    for (int j = 0; j < 4; ++j){         // this thread's bk segments: seg0+j<16 iff w<2
      int seg = seg0 + j;
      if (seg < 16){
        int row = (seg << 1) + (lane >> 5);
        int chunk = (lane & 31) ^ (row & 7);
        srow[j] = row; schk[j] = lane & 31;
        st[j] = *(const uint4*)(bkrm + ((size_t)(c*512 + kabs + row))*256 + chunk*8);
      } else {
        int t2 = seg - 16;
        int d = (t2 << 4) + (lane >> 2);
        int slot = (lane & 3) ^ (d & 3);
        sd[j] = d; sslot[j] = lane & 3;
        st[j] = *(const uint4*)(bkTg + ((size_t)(c*256 + d))*512 + kabs + slot*8);
      }
    }
    int srow2[4], schk2[4], sd2[4], sslot2[4];
    #pragma unroll
    for (int j = 4; j < 8; ++j){
      int seg = seg0 + j;
      if (seg < 16){
        int row = (seg << 1) + (lane >> 5);
        int chunk = (lane & 31) ^ (row & 7);
        srow2[j-4] = row; schk2[j-4] = lane & 31;
        st[j] = *(const uint4*)(bkrm + ((size_t)(c*512 + kabs + row))*256 + chunk*8);
      } else {
        int t2 = seg - 16;
        int d = (t2 << 4) + (lane >> 2);
        int slot = (lane & 3) ^ (d & 3);
        sd2[j-4] = d; sslot2[j-4] = lane & 3;
        st[j] = *(const uint4*)(bkTg + ((size_t)(c*256 + d))*512 + kabs + slot*8);
      }
    }
    // ---- gumbels (long independent VALU chain; covers load latency) ----
    float gv0[4], gv1[4];
    {
      uint32_t kidx = nb + (uint32_t)(kabs + 4*g);
      #pragma unroll
      for (int i = 0; i < 4; ++i){
        gv0[i] = gum_at(ke0, ke1, kidx + (uint32_t)i);
        gv1[i] = gum_at(ke0, ke1, kidx + 16u + (uint32_t)i);
      }
    }
    float4 as0 = *(const float4*)(ws + F_AS + c*512 + kabs + 4*g);
    float4 as1 = *(const float4*)(ws + F_AS + c*512 + kabs + 16 + 4*g);
    __syncthreads();   // all waves done reading previous tile
    // ---- write staged data to LDS ----
    #pragma unroll
    for (int j = 0; j < 4; ++j){
      int seg = seg0 + j;
      if (seg < 16)
        *(uint4*)(sm + (srow[j] << 9) + (schk[j] << 4)) = st[j];
      else
        *(uint4*)(sm + 16384 + (sd[j] << 6) + (sslot[j] << 4)) = st[j];
    }
    #pragma unroll
    for (int j = 4; j < 8; ++j){
      int seg = seg0 + j;
      if (seg < 16)
        *(uint4*)(sm + (srow2[j-4] << 9) + (schk2[j-4] << 4)) = st[j];
      else
        *(uint4*)(sm + 16384 + (sd2[j-4] << 6) + (sslot2[j-4] << 4)) = st[j];
    }
    __syncthreads();   // tile ready
    // ---- QK from LDS: S^T = mfma(bk_frag, za) ----
    f32x4 a0 = (f32x4)(0.f), a1 = (f32x4)(0.f);
    #pragma unroll
    for (int dt = 0; dt < 8; ++dt){
      int chunk0 = ((dt << 2) + g) ^ (r16 & 7);
      bf16x8 f0 = *(const bf16x8*)(sm + (r16 << 9) + (chunk0 << 4));
      bf16x8 f1 = *(const bf16x8*)(sm + ((16 + r16) << 9) + (chunk0 << 4));
      a0 = __builtin_amdgcn_mfma_f32_16x16x32_bf16(f0, za[dt], a0, 0, 0, 0);
      a1 = __builtin_amdgcn_mfma_f32_16x16x32_bf16(f1, za[dt], a1, 0, 0, 0);
    }
    float v0[4], v1[4];
    v0[0] = fmaf(fourpq, a0[0], fmaf(2.f, gv0[0], as0.x));
    v0[1] = fmaf(fourpq, a0[1], fmaf(2.f, gv0[1], as0.y));
    v0[2] = fmaf(fourpq, a0[2], fmaf(2.f, gv0[2], as0.z));
    v0[3] = fmaf(fourpq, a0[3], fmaf(2.f, gv0[3], as0.w));
    v1[0] = fmaf(fourpq, a1[0], fmaf(2.f, gv1[0], as1.x));
    v1[1] = fmaf(fourpq, a1[1], fmaf(2.f, gv1[1], as1.y));
    v1[2] = fmaf(fourpq, a1[2], fmaf(2.f, gv1[2], as1.z));
    v1[3] = fmaf(fourpq, a1[3], fmaf(2.f, gv1[3], as1.w));
    // per-n max (n = r16; partners at xor 16/32)
    float mr = fmaxf(fmaxf(fmaxf(v0[0], v0[1]), fmaxf(v0[2], v0[3])),
                     fmaxf(fmaxf(v1[0], v1[1]), fmaxf(v1[2], v1[3])));
    mr = fmaxf(mr, __shfl_xor(mr, 16));
    mr = fmaxf(mr, __shfl_xor(mr, 32));
    if (__any(mr > m + 8.f)){
      float mn = fmaxf(m, mr);
      float sc = __expf(m - mn);
      m = mn; l *= sc;
      float s0_ = __shfl(sc, 4*g + 0);
      float s1_ = __shfl(sc, 4*g + 1);
      float s2_ = __shfl(sc, 4*g + 2);
      float s3_ = __shfl(sc, 4*g + 3);
      #pragma unroll
      for (int dt = 0; dt < 16; ++dt){
        o[dt][0] *= s0_; o[dt][1] *= s1_; o[dt][2] *= s2_; o[dt][3] *= s3_;
      }
    }
    float p0[4], p1[4];
    #pragma unroll
    for (int i = 0; i < 4; ++i){
      p0[i] = __expf(v0[i] - m);
      p1[i] = __expf(v1[i] - m);
      l += p0[i] + p1[i];
    }
    // pack P and exchange via register permutation (verified R7)
    uint32_t wlox = pk2(p0[0], p0[1]), wloy = pk2(p0[2], p0[3]);
    uint32_t whix = pk2(p1[0], p1[1]), whiy = pk2(p1[2], p1[3]);
    union U8 { bf16x8 f; uint32_t u[4]; } pa;
    {
      uint32_t aLx = __shfl((int)wlox, srcA), aHx = __shfl((int)whix, srcA);
      uint32_t aLy = __shfl((int)wloy, srcA), aHy = __shfl((int)whiy, srcA);
      uint32_t bLx = __shfl((int)wlox, srcB), bHx = __shfl((int)whix, srcB);
      uint32_t bLy = __shfl((int)wloy, srcB), bHy = __shfl((int)whiy, srcB);
      pa.u[0] = selhi ? aHx : aLx;
      pa.u[1] = selhi ? aHy : aLy;
      pa.u[2] = selhi ? bHx : bLx;
      pa.u[3] = selhi ? bHy : bLy;
    }
    // ---- PV from LDS bkT tile ----
    #pragma unroll
    for (int dt = 0; dt < 16; ++dt){
      int d = (dt << 4) + r16;
      bf16x8 fv = *(const bf16x8*)(sm + 16384 + (d << 6) + ((g ^ (d & 3)) << 4));
      o[dt] = __builtin_amdgcn_mfma_f32_16x16x32_bf16(pa.f, fv, o[dt], 0, 0, 0);
    }
  }

  float lt = l;
  lt += __shfl_xor(lt, 16);
  lt += __shfl_xor(lt, 32);
  size_t rowb = ((size_t)((b*10 + c)*2 + h))*256 + n0;
  if (g == 0) lseg[rowb + r16] = m + __logf(lt);
  float invl = 1.0f / lt;
  float f0 = __shfl(invl, 4*g + 0);
  float f1 = __shfl(invl, 4*g + 1);
  float f2 = __shfl(invl, 4*g + 2);
  float f3 = __shfl(invl, 4*g + 3);
  uint16_t* dst = part + (rowb + 4*g)*256 + r16;
  #pragma unroll
  for (int dt = 0; dt < 16; ++dt){
    dst[0*256 + dt*16] = bfbits(o[dt][0] * f0);
    dst[1*256 + dt*16] = bfbits(o[dt][1] * f1);
    dst[2*256 + dt*16] = bfbits(o[dt][2] * f2);
    dst[3*256 + dt*16] = bfbits(o[dt][3] * f3);
  }
}

// ---------------------------------------------------------------------------
// k_comb: zq[b,n,:] = sum_{c,h} coef * Ohat.  grid 1024 x 256 (8 rows/blk).
// ---------------------------------------------------------------------------
__global__ void __launch_bounds__(256)
k_comb(const uint16_t* __restrict__ part, const float* __restrict__ lseg,
       const float* __restrict__ ws, float* __restrict__ zq){
  __shared__ float coef[8][20];
  int row0 = blockIdx.x * 8;
  int t = threadIdx.x;
  if (t < 80){
    int rr = t / 10, c = t % 10;
    int rw = row0 + rr, b = rw >> 8, n = rw & 255;
    float cp = ws[F_CP + b * 10 + c];
    size_t base = ((size_t)((b*10 + c)*2))*256 + n;
    float l0 = lseg[base], l1 = lseg[base + 256];
    float mx = fmaxf(l0, l1);
    float e0 = __expf(l0 - mx), e1 = __expf(l1 - mx);
    float inv = cp / (e0 + e1);
    coef[rr][c * 2]     = e0 * inv;
    coef[rr][c * 2 + 1] = e1 * inv;
  }
  __syncthreads();
  int rr = t >> 5, dc = (t & 31) << 3;
  int rw = row0 + rr, b = rw >> 8, n = rw & 255;
  float acc[8];
  #pragma unroll
  for (int j = 0; j < 8; ++j) acc[j] = 0.f;
  #pragma unroll
  for (int c = 0; c < 10; ++c){
    #pragma unroll
    for (int h = 0; h < 2; ++h){
      float wv = coef[rr][c * 2 + h];
      const uint16_t* p = part + (((size_t)((b*10 + c)*2 + h))*256 + n)*256 + dc;
      uint4 v = *(const uint4*)p;
      uint32_t uu[4] = {v.x, v.y, v.z, v.w};
      #pragma unroll
      for (int q = 0; q < 4; ++q){
        acc[2*q]   = fmaf(wv, bflo(uu[q]), acc[2*q]);
        acc[2*q+1] = fmaf(wv, bfhi(uu[q]), acc[2*q+1]);
      }
    }
  }
  float* dstp = zq + ((size_t)(b*256 + n))*256 + dc;
  float4 r0 = {acc[0], acc[1], acc[2], acc[3]};
  float4 r1 = {acc[4], acc[5], acc[6], acc[7]};
  *(float4*)dstp = r0;
  *(float4*)(dstp + 4) = r1;
}

// ---------------------------------------------------------------------------
extern "C" void kernel_launch(void* const* d_in, const int* in_sizes, int n_in,
                              void* d_out, int out_size, void* d_ws, size_t ws_size,
                              hipStream_t stream){
  (void)in_sizes; (void)n_in; (void)out_size; (void)ws_size;
  const float* ze    = (const float*)d_in[0];
  const float* cl    = (const float*)d_in[1];
  const float* books = (const float*)d_in[2];
  const float* lpq   = (const float*)d_in[3];
  const float* lpqc  = (const float*)d_in[4];
  float* out  = (float*)d_out;
  float* ws   = (float*)d_ws;
  float* zq   = out;
  float* prob = out + 2097153;
  float* logp = out + 2097153 + 4194304;

  uint16_t* bkrm = (uint16_t*)(ws + O_BKRM);
  uint16_t* bkTg = (uint16_t*)(ws + O_BKT);
  uint16_t* Mh   = (uint16_t*)(ws + O_MH);
  uint16_t* partp= (uint16_t*)(ws + O_PART);
  float*    lsegp= ws + F_LSE;

  k_prep<<<80, 256, 0, stream>>>(books, cl, lpq, lpqc, ws, out, bkrm, bkTg);
  k_mix<<<4096, 256, 0, stream>>>(bkrm, lpq, ws, Mh);
  k_probs_mf<<<512, 128, 0, stream>>>(ze, Mh, ws, lpq, prob, logp);
  k_zq_st<<<2560, 256, 0, stream>>>(ze, bkrm, bkTg, ws, lpq, partp, lsegp);
  k_comb<<<1024, 256, 0, stream>>>(partp, lsegp, ws, zq);
}

// Round 10
// 349.065 us; speedup vs baseline: 1.9675x; 1.9675x over previous
//
#include <hip/hip_runtime.h>
#include <stdint.h>

// ---------------------------------------------------------------------------
// GaussianVectorQuantizer (training) MI355X.
// Outputs (flat f32): zq[2097152] | precision_q[1] | prob[4194304] | log_prob[4194304]
// RNG (verified R2): threefry2x32 partitionable, fold-like split, draw = o0^o1.
// R10: k_zq = R4's prefetch-depth-1 LDS pipeline (proven 253us @ 67% VALU)
//      x R7's S^T orientation + shuffle P-exchange (no P-buffer, no bk2 tile),
//      512-thr blocks, grid 1280, c-slowest XCD swizzle. k_probs = R7 version.
// ---------------------------------------------------------------------------

typedef __attribute__((ext_vector_type(8))) __bf16 bf16x8;
typedef __attribute__((ext_vector_type(4))) float f32x4;

// ws float-offsets
#define F_CP     0
#define F_BK2    512
#define F_AS     5632
#define F_ASUM   10752
#define F_LSE    27136
#define O_BKRM   190976u
#define O_BKT    846336u
#define O_MH     1501696u
#define O_PART   1501696u   // overlays Mh (k_zq runs after k_probs)

__device__ __forceinline__ uint32_t rotl32(uint32_t x, int r){ return (x << r) | (x >> (32 - r)); }

__device__ __forceinline__ void tf2x32(uint32_t k0, uint32_t k1, uint32_t x0, uint32_t x1,
                                       uint32_t &o0, uint32_t &o1){
  uint32_t k2 = k0 ^ k1 ^ 0x1BD11BDAu;
  x0 += k0; x1 += k1;
#define TFR(r) { x0 += x1; x1 = rotl32(x1,(r)); x1 ^= x0; }
  TFR(13) TFR(15) TFR(26) TFR(6)
  x0 += k1; x1 += k2 + 1u;
  TFR(17) TFR(29) TFR(16) TFR(24)
  x0 += k2; x1 += k0 + 2u;
  TFR(13) TFR(15) TFR(26) TFR(6)
  x0 += k0; x1 += k1 + 3u;
  TFR(17) TFR(29) TFR(16) TFR(24)
  x0 += k1; x1 += k2 + 4u;
  TFR(13) TFR(15) TFR(26) TFR(6)
  x0 += k2; x1 += k0 + 5u;
#undef TFR
  o0 = x0; o1 = x1;
}

__device__ __forceinline__ uint32_t rbits0(uint32_t k0, uint32_t k1, uint32_t i){
  uint32_t o0, o1; tf2x32(k0, k1, 0u, i, o0, o1); return o0 ^ o1;
}
__device__ __forceinline__ float bits_to_u01(uint32_t b){
  return __uint_as_float((b >> 9) | 0x3F800000u) - 1.0f;
}
__device__ __forceinline__ float gumbel_u(float u){
  return -__logf(-__logf(u + 1e-10f) + 1e-10f);
}
__device__ __forceinline__ float gum_at(uint32_t k0, uint32_t k1, uint32_t idx){
  return gumbel_u(bits_to_u01(rbits0(k0, k1, idx)));
}
__device__ __forceinline__ uint16_t bfbits(float x){
  union { __bf16 h; uint16_t s; } u; u.h = (__bf16)x; return u.s;
}
__device__ __forceinline__ uint32_t pk2(float a, float b){
  return (uint32_t)bfbits(a) | ((uint32_t)bfbits(b) << 16);
}
__device__ __forceinline__ float bflo(uint32_t u){ return __uint_as_float((u & 0xFFFFu) << 16); }
__device__ __forceinline__ float bfhi(uint32_t u){ return __uint_as_float((u >> 16) << 16); }

// ---------------------------------------------------------------------------
// k_prep: books -> bkrm bf16 + bkT bf16; bk2 + As = -2pq*bk2; cprob; precision_q.
// grid 80 = c(10) x k0(8 tiles of 64 rows), 256 threads.
// ---------------------------------------------------------------------------
__global__ void __launch_bounds__(256)
k_prep(const float* __restrict__ books, const float* __restrict__ c_logits,
       const float* __restrict__ lpq, const float* __restrict__ lpqc,
       float* __restrict__ ws, float* __restrict__ out,
       uint16_t* __restrict__ bkrm, uint16_t* __restrict__ bkTg){
  __shared__ __align__(16) char tsm[32768];   // [64][256] bf16, swizzled
  int c = blockIdx.x >> 3, k0 = (blockIdx.x & 7) << 6;
  int t = threadIdx.x, lane = t & 63, w4 = t >> 6;
  float pq = 0.5f / fmaxf(1.0f + __expf(lpq[0]), 1e-10f);
  #pragma unroll
  for (int q = 0; q < 16; ++q){
    int kk = q * 4 + w4, d = lane * 4;
    float4 v = *(const float4*)(books + ((size_t)(c*512 + k0 + kk))*256 + d);
    float s = v.x*v.x + v.y*v.y + v.z*v.z + v.w*v.w;
    #pragma unroll
    for (int m = 1; m < 64; m <<= 1) s += __shfl_xor(s, m);
    if (lane == 0){
      ws[F_BK2 + c*512 + k0 + kk] = s;
      ws[F_AS  + c*512 + k0 + kk] = -2.0f * pq * s;
    }
    uint2 h; h.x = pk2(v.x, v.y); h.y = pk2(v.z, v.w);
    *(uint2*)(bkrm + ((size_t)(c*512 + k0 + kk))*256 + d) = h;
    int base = (kk << 9) + (d << 1);
    *(uint2*)(tsm + (base ^ ((kk & 7) << 4))) = h;
  }
  __syncthreads();
  {
    int d = t;
    uint16_t tmp[64];
    #pragma unroll
    for (int kk = 0; kk < 64; ++kk)
      tmp[kk] = *(uint16_t*)(tsm + (((kk << 9) + (d << 1)) ^ ((kk & 7) << 4)));
    #pragma unroll
    for (int q = 0; q < 8; ++q)
      *(uint4*)(bkTg + ((size_t)(c*256 + d))*512 + k0 + q*8) = *(uint4*)&tmp[q*8];
  }
  if (blockIdx.x == 0){
    if (t == 0) out[2097152] = pq;
    if (t < 32){
      int b = t;
      float pqc = 0.5f / fmaxf(1.0f + __expf(lpqc[0]), 1e-10f);
      uint32_t kc0, kc1; tf2x32(0u, 42u, 0u, 0u, kc0, kc1);
      float y[10]; float mx = -1e30f;
      #pragma unroll
      for (int c2 = 0; c2 < 10; ++c2){
        float g = gum_at(kc0, kc1, (uint32_t)(b * 10 + c2));
        float v = (c_logits[b * 10 + c2] * pqc + g) * 2.0f;
        y[c2] = v; mx = fmaxf(mx, v);
      }
      float s = 0.f;
      #pragma unroll
      for (int c2 = 0; c2 < 10; ++c2){ y[c2] = __expf(y[c2] - mx); s += y[c2]; }
      float inv = 1.0f / s;
      #pragma unroll
      for (int c2 = 0; c2 < 10; ++c2) ws[F_CP + b * 10 + c2] = y[c2] * inv;
    }
  }
}

// ---------------------------------------------------------------------------
// k_mix: Mh[b][k][d] = sum_c cp*bkrm  (bf16);  Asum[b][k] = -pq*sum_c cp*bk2.
// grid 4096 = b(32) x kgroup(128 of 4 rows), 256 threads.
// ---------------------------------------------------------------------------
__global__ void __launch_bounds__(256)
k_mix(const uint16_t* __restrict__ bkrm, const float* __restrict__ lpq,
      float* __restrict__ ws, uint16_t* __restrict__ Mh){
  int blk = blockIdx.x;
  int b = blk >> 7, kg = blk & 127;
  int t = threadIdx.x, kr = t >> 6, lane = t & 63;
  int k = kg * 4 + kr, d = lane * 4;
  float a0=0.f, a1=0.f, a2=0.f, a3=0.f;
  float cp[10];
  #pragma unroll
  for (int c = 0; c < 10; ++c) cp[c] = ws[F_CP + b*10 + c];
  #pragma unroll
  for (int c = 0; c < 10; ++c){
    uint2 v = *(const uint2*)(bkrm + ((size_t)(c*512 + k))*256 + d);
    a0 = fmaf(cp[c], bflo(v.x), a0); a1 = fmaf(cp[c], bfhi(v.x), a1);
    a2 = fmaf(cp[c], bflo(v.y), a2); a3 = fmaf(cp[c], bfhi(v.y), a3);
  }
  uint2 h; h.x = pk2(a0, a1); h.y = pk2(a2, a3);
  *(uint2*)(Mh + ((size_t)(b*512 + k))*256 + d) = h;
  if (lane == 0){
    float pq = 0.5f / fmaxf(1.0f + __expf(lpq[0]), 1e-10f);
    float s = 0.f;
    #pragma unroll
    for (int c = 0; c < 10; ++c) s = fmaf(cp[c], ws[F_BK2 + c*512 + k], s);
    ws[F_ASUM + b*512 + k] = -pq * s;
  }
}

// ---------------------------------------------------------------------------
// k_probs_mf: prob/log_prob via MFMA (S^T orientation, online LSE, one pass).
// grid 256 x 128 thr (2 waves); wave = (b, 16-row n-tile), full k=512 in regs.
// ---------------------------------------------------------------------------
__global__ void __launch_bounds__(128)
k_probs_mf(const float* __restrict__ ze, const uint16_t* __restrict__ Mh,
           const float* __restrict__ ws, const float* __restrict__ lpq,
           float* __restrict__ prob, float* __restrict__ logp){
  int wid = blockIdx.x * 2 + (threadIdx.x >> 6);
  int b = wid >> 4, n0 = (wid & 15) << 4;
  int lane = threadIdx.x & 63, g = lane >> 4, r16 = lane & 15;
  float pq = 0.5f / fmaxf(1.0f + __expf(lpq[0]), 1e-10f);
  float twopq = 2.0f * pq;

  bf16x8 za[8];
  {
    const float* zp = ze + ((size_t)(b * 256 + n0 + r16)) * 256 + g * 8;
    #pragma unroll
    for (int dt = 0; dt < 8; ++dt){
      float4 v0 = *(const float4*)(zp + dt * 32);
      float4 v1 = *(const float4*)(zp + dt * 32 + 4);
      bf16x8 z;
      z[0]=(__bf16)v0.x; z[1]=(__bf16)v0.y; z[2]=(__bf16)v0.z; z[3]=(__bf16)v0.w;
      z[4]=(__bf16)v1.x; z[5]=(__bf16)v1.y; z[6]=(__bf16)v1.z; z[7]=(__bf16)v1.w;
      za[dt] = z;
    }
  }

  f32x4 va[16], vb[16];
  float m = -1e30f, l = 0.f;
  #pragma unroll
  for (int p = 0; p < 16; ++p){
    int kabs = p << 5;
    const uint16_t* s0 = Mh + ((size_t)(b*512 + kabs + r16))*256 + g*8;
    const uint16_t* s1 = s0 + (size_t)16*256;
    f32x4 a0 = (f32x4)(0.f), a1 = (f32x4)(0.f);
    #pragma unroll
    for (int dt = 0; dt < 8; ++dt){
      bf16x8 f0 = *(const bf16x8*)(s0 + dt*32);
      bf16x8 f1 = *(const bf16x8*)(s1 + dt*32);
      a0 = __builtin_amdgcn_mfma_f32_16x16x32_bf16(f0, za[dt], a0, 0, 0, 0);
      a1 = __builtin_amdgcn_mfma_f32_16x16x32_bf16(f1, za[dt], a1, 0, 0, 0);
    }
    float4 as0 = *(const float4*)(ws + F_ASUM + b*512 + kabs + 4*g);
    float4 as1 = *(const float4*)(ws + F_ASUM + b*512 + kabs + 16 + 4*g);
    f32x4 v0, v1;
    v0[0] = fmaf(twopq, a0[0], as0.x); v0[1] = fmaf(twopq, a0[1], as0.y);
    v0[2] = fmaf(twopq, a0[2], as0.z); v0[3] = fmaf(twopq, a0[3], as0.w);
    v1[0] = fmaf(twopq, a1[0], as1.x); v1[1] = fmaf(twopq, a1[1], as1.y);
    v1[2] = fmaf(twopq, a1[2], as1.z); v1[3] = fmaf(twopq, a1[3], as1.w);
    va[p] = v0; vb[p] = v1;
    float mr = fmaxf(fmaxf(fmaxf(v0[0], v0[1]), fmaxf(v0[2], v0[3])),
                     fmaxf(fmaxf(v1[0], v1[1]), fmaxf(v1[2], v1[3])));
    mr = fmaxf(mr, __shfl_xor(mr, 16));
    mr = fmaxf(mr, __shfl_xor(mr, 32));
    float mn = fmaxf(m, mr);
    float sc = __expf(m - mn);
    float cs = 0.f;
    #pragma unroll
    for (int i = 0; i < 4; ++i) cs += __expf(v0[i] - mn);
    #pragma unroll
    for (int i = 0; i < 4; ++i) cs += __expf(v1[i] - mn);
    l = l * sc + cs;
    m = mn;
  }
  l += __shfl_xor(l, 16);
  l += __shfl_xor(l, 32);
  float lse = m + __logf(l);
  float* pb = prob + ((size_t)(b*256 + n0 + r16))*512;
  float* lb = logp + ((size_t)(b*256 + n0 + r16))*512;
  #pragma unroll
  for (int p = 0; p < 16; ++p){
    int kabs = (p << 5) + 4*g;
    f32x4 v0 = va[p], v1 = vb[p];
    float4 l0 = {v0[0]-lse, v0[1]-lse, v0[2]-lse, v0[3]-lse};
    float4 l1 = {v1[0]-lse, v1[1]-lse, v1[2]-lse, v1[3]-lse};
    float4 p0 = {__expf(l0.x), __expf(l0.y), __expf(l0.z), __expf(l0.w)};
    float4 p1 = {__expf(l1.x), __expf(l1.y), __expf(l1.z), __expf(l1.w)};
    *(float4*)(lb + kabs)      = l0;
    *(float4*)(lb + kabs + 16) = l1;
    *(float4*)(pb + kabs)      = p0;
    *(float4*)(pb + kabs + 16) = p1;
  }
}

// ---------------------------------------------------------------------------
// k_zq_p: pipelined LDS-staged flash zq (R4 pipeline x R7 S^T softmax).
// grid 1280 = c(10, slowest) x b(32) x nt(2 of 128 rows) x h(2 k-halves),
// 512 thr (8 waves x 16 rows). Per k-pair(32): barrier -> write staged regs
// to LDS -> barrier -> prefetch next pair -> QK(S^T) -> softmax -> shuffle
// P-exchange -> PV. LDS 32KB: bk [32k][256d] swz | bkT [256d][32k] packed swz.
// ---------------------------------------------------------------------------
__global__ void __launch_bounds__(512)
k_zq_p(const float* __restrict__ ze, const uint16_t* __restrict__ bkrm,
       const uint16_t* __restrict__ bkTg, const float* __restrict__ ws,
       const float* __restrict__ lpq, uint16_t* __restrict__ part,
       float* __restrict__ lseg){
  __shared__ __align__(16) char sm[32768];
  int bid = blockIdx.x;
  int wg = (bid & 7) * 160 + (bid >> 3);     // bijective (1280 % 8 == 0)
  int c = wg >> 7;                           // c slowest: 128 blocks per c
  int rem = wg & 127;
  int b = rem >> 2, r2 = rem & 3, nt = r2 >> 1, h = r2 & 1;
  int tid = threadIdx.x, w = tid >> 6, lane = tid & 63, g = lane >> 4, r16 = lane & 15;
  int n0 = nt * 128 + w * 16;
  const int kb0 = h << 8;
  float pq = 0.5f / fmaxf(1.0f + __expf(lpq[0]), 1e-10f);
  float fourpq = 4.0f * pq;
  uint32_t ke0, ke1; tf2x32(0u, 42u, 0u, 1u, ke0, ke1);
  const int srcA = (g & 1) * 32 + r16;       // P-exchange source lanes (R7)
  const int srcB = srcA + 16;
  const bool selhi = (g >= 2);

  bf16x8 za[8];
  {
    const float* zp = ze + ((size_t)(b * 256 + n0 + r16)) * 256 + g * 8;
    #pragma unroll
    for (int dt = 0; dt < 8; ++dt){
      float4 v0 = *(const float4*)(zp + dt * 32);
      float4 v1 = *(const float4*)(zp + dt * 32 + 4);
      bf16x8 z;
      z[0]=(__bf16)v0.x; z[1]=(__bf16)v0.y; z[2]=(__bf16)v0.z; z[3]=(__bf16)v0.w;
      z[4]=(__bf16)v1.x; z[5]=(__bf16)v1.y; z[6]=(__bf16)v1.z; z[7]=(__bf16)v1.w;
      za[dt] = z;
    }
  }

  f32x4 o[16];
  #pragma unroll
  for (int i = 0; i < 16; ++i) o[i] = (f32x4)(0.f);
  float m = -1e30f, l = 0.f;
  const uint32_t nb = ((uint32_t)((b*10 + c)*256 + n0 + r16)) << 9;

  // staging thread mapping (constant over pairs) — R4's proven layout
  const int sk = tid >> 4, sd16 = (tid & 15) << 4;                 // bk rows
  const int td = tid >> 1, tkh = (tid & 1) << 4;                   // bkT rows
  uint4 pf0, pf1, pf2, pf3;
  auto LOADP = [&](int p){
    int kabs = kb0 + p * 32;
    const uint4* s1 = (const uint4*)(bkrm + ((size_t)(c*512 + kabs + sk))*256 + sd16);
    pf0 = s1[0]; pf1 = s1[1];
    const uint4* s2 = (const uint4*)(bkTg + ((size_t)(c*256 + td))*512 + kabs + tkh);
    pf2 = s2[0]; pf3 = s2[1];
  };
  LOADP(0);

  for (int p = 0; p < 8; ++p){
    const int kabs = kb0 + (p << 5);
    __syncthreads();
    { // write staged regs to LDS (R4 addressing)
      int base = (sk << 9) + (sd16 << 1), sw = (sk & 7) << 4;
      *(uint4*)(sm + ( base       ^ sw)) = pf0;
      *(uint4*)(sm + ((base + 16) ^ sw)) = pf1;
      int base2 = 16384 + ((td >> 1) << 7) + ((((td & 1) << 5) + tkh) << 1);
      int sw2 = ((td >> 1) & 7) << 4;
      *(uint4*)(sm + ( base2       ^ sw2)) = pf2;
      *(uint4*)(sm + ((base2 + 16) ^ sw2)) = pf3;
    }
    __syncthreads();
    if (p + 1 < 8) LOADP(p + 1);   // prefetch: full compute phase to cover

    // gumbels (independent VALU; overlaps prefetch latency)
    float gv0[4], gv1[4];
    {
      uint32_t kidx = nb + (uint32_t)(kabs + 4*g);
      #pragma unroll
      for (int i = 0; i < 4; ++i){
        gv0[i] = gum_at(ke0, ke1, kidx + (uint32_t)i);
        gv1[i] = gum_at(ke0, ke1, kidx + 16u + (uint32_t)i);
      }
    }
    float4 as0 = *(const float4*)(ws + F_AS + c*512 + kabs + 4*g);
    float4 as1 = *(const float4*)(ws + F_AS + c*512 + kabs + 16 + 4*g);

    // QK from LDS, S^T: rows k (r16 / 16+r16), cols n (za as B-operand)
    f32x4 a0 = (f32x4)(0.f), a1 = (f32x4)(0.f);
    #pragma unroll
    for (int dt = 0; dt < 8; ++dt){
      int d0b = ((dt * 32 + g * 8) << 1);
      int row0 = r16, row1 = 16 + r16;
      bf16x8 f0 = *(const bf16x8*)(sm + (((row0 << 9) + d0b) ^ ((row0 & 7) << 4)));
      bf16x8 f1 = *(const bf16x8*)(sm + (((row1 << 9) + d0b) ^ ((row1 & 7) << 4)));
      a0 = __builtin_amdgcn_mfma_f32_16x16x32_bf16(f0, za[dt], a0, 0, 0, 0);
      a1 = __builtin_amdgcn_mfma_f32_16x16x32_bf16(f1, za[dt], a1, 0, 0, 0);
    }
    float v0[4], v1[4];
    v0[0] = fmaf(fourpq, a0[0], fmaf(2.f, gv0[0], as0.x));
    v0[1] = fmaf(fourpq, a0[1], fmaf(2.f, gv0[1], as0.y));
    v0[2] = fmaf(fourpq, a0[2], fmaf(2.f, gv0[2], as0.z));
    v0[3] = fmaf(fourpq, a0[3], fmaf(2.f, gv0[3], as0.w));
    v1[0] = fmaf(fourpq, a1[0], fmaf(2.f, gv1[0], as1.x));
    v1[1] = fmaf(fourpq, a1[1], fmaf(2.f, gv1[1], as1.y));
    v1[2] = fmaf(fourpq, a1[2], fmaf(2.f, gv1[2], as1.z));
    v1[3] = fmaf(fourpq, a1[3], fmaf(2.f, gv1[3], as1.w));
    // per-n max (n = r16; partners at xor 16/32)
    float mr = fmaxf(fmaxf(fmaxf(v0[0], v0[1]), fmaxf(v0[2], v0[3])),
                     fmaxf(fmaxf(v1[0], v1[1]), fmaxf(v1[2], v1[3])));
    mr = fmaxf(mr, __shfl_xor(mr, 16));
    mr = fmaxf(mr, __shfl_xor(mr, 32));
    if (__any(mr > m + 8.f)){
      float mn = fmaxf(m, mr);
      float sc = __expf(m - mn);
      m = mn; l *= sc;
      float s0_ = __shfl(sc, 4*g + 0);
      float s1_ = __shfl(sc, 4*g + 1);
      float s2_ = __shfl(sc, 4*g + 2);
      float s3_ = __shfl(sc, 4*g + 3);
      #pragma unroll
      for (int dt = 0; dt < 16; ++dt){
        o[dt][0] *= s0_; o[dt][1] *= s1_; o[dt][2] *= s2_; o[dt][3] *= s3_;
      }
    }
    float p0[4], p1[4];
    #pragma unroll
    for (int i = 0; i < 4; ++i){
      p0[i] = __expf(v0[i] - m);
      p1[i] = __expf(v1[i] - m);
      l += p0[i] + p1[i];
    }
    // pack P and exchange via register permutation (verified R7)
    uint32_t wlox = pk2(p0[0], p0[1]), wloy = pk2(p0[2], p0[3]);
    uint32_t whix = pk2(p1[0], p1[1]), whiy = pk2(p1[2], p1[3]);
    union U8 { bf16x8 f; uint32_t u[4]; } pa;
    {
      uint32_t aLx = __shfl((int)wlox, srcA), aHx = __shfl((int)whix, srcA);
      uint32_t aLy = __shfl((int)wloy, srcA), aHy = __shfl((int)whiy, srcA);
      uint32_t bLx = __shfl((int)wlox, srcB), bHx = __shfl((int)whix, srcB);
      uint32_t bLy = __shfl((int)wloy, srcB), bHy = __shfl((int)whiy, srcB);
      pa.u[0] = selhi ? aHx : aLx;
      pa.u[1] = selhi ? aHy : aLy;
      pa.u[2] = selhi ? bHx : bLx;
      pa.u[3] = selhi ? bHy : bLy;
    }
    // PV from LDS bkT tile (R4 addressing)
    #pragma unroll
    for (int dt = 0; dt < 16; ++dt){
      int d = (dt << 4) + r16;
      int base = 16384 + ((d >> 1) << 7) + ((((d & 1) << 5) + (g << 3)) << 1);
      int sw = ((d >> 1) & 7) << 4;
      U8 bf;
      *(uint2*)&bf.u[0] = *(const uint2*)(sm + ( base      ^ sw));
      *(uint2*)&bf.u[2] = *(const uint2*)(sm + ((base + 8) ^ sw));
      o[dt] = __builtin_amdgcn_mfma_f32_16x16x32_bf16(pa.f, bf.f, o[dt], 0, 0, 0);
    }
  }

  float lt = l;
  lt += __shfl_xor(lt, 16);
  lt += __shfl_xor(lt, 32);
  size_t rowb = ((size_t)((b*10 + c)*2 + h))*256 + n0;
  if (g == 0) lseg[rowb + r16] = m + __logf(lt);
  float invl = 1.0f / lt;
  float f0 = __shfl(invl, 4*g + 0);
  float f1 = __shfl(invl, 4*g + 1);
  float f2 = __shfl(invl, 4*g + 2);
  float f3 = __shfl(invl, 4*g + 3);
  uint16_t* dst = part + (rowb + 4*g)*256 + r16;
  #pragma unroll
  for (int dt = 0; dt < 16; ++dt){
    dst[0*256 + dt*16] = bfbits(o[dt][0] * f0);
    dst[1*256 + dt*16] = bfbits(o[dt][1] * f1);
    dst[2*256 + dt*16] = bfbits(o[dt][2] * f2);
    dst[3*256 + dt*16] = bfbits(o[dt][3] * f3);
  }
}

// ---------------------------------------------------------------------------
// k_comb: zq[b,n,:] = sum_{c,h} coef * Ohat.  grid 1024 x 256 (8 rows/blk).
// ---------------------------------------------------------------------------
__global__ void __launch_bounds__(256)
k_comb(const uint16_t* __restrict__ part, const float* __restrict__ lseg,
       const float* __restrict__ ws, float* __restrict__ zq){
  __shared__ float coef[8][20];
  int row0 = blockIdx.x * 8;
  int t = threadIdx.x;
  if (t < 80){
    int rr = t / 10, c = t % 10;
    int rw = row0 + rr, b = rw >> 8, n = rw & 255;
    float cp = ws[F_CP + b * 10 + c];
    size_t base = ((size_t)((b*10 + c)*2))*256 + n;
    float l0 = lseg[base], l1 = lseg[base + 256];
    float mx = fmaxf(l0, l1);
    float e0 = __expf(l0 - mx), e1 = __expf(l1 - mx);
    float inv = cp / (e0 + e1);
    coef[rr][c * 2]     = e0 * inv;
    coef[rr][c * 2 + 1] = e1 * inv;
  }
  __syncthreads();
  int rr = t >> 5, dc = (t & 31) << 3;
  int rw = row0 + rr, b = rw >> 8, n = rw & 255;
  float acc[8];
  #pragma unroll
  for (int j = 0; j < 8; ++j) acc[j] = 0.f;
  #pragma unroll
  for (int c = 0; c < 10; ++c){
    #pragma unroll
    for (int h = 0; h < 2; ++h){
      float wv = coef[rr][c * 2 + h];
      const uint16_t* p = part + (((size_t)((b*10 + c)*2 + h))*256 + n)*256 + dc;
      uint4 v = *(const uint4*)p;
      uint32_t uu[4] = {v.x, v.y, v.z, v.w};
      #pragma unroll
      for (int q = 0; q < 4; ++q){
        acc[2*q]   = fmaf(wv, bflo(uu[q]), acc[2*q]);
        acc[2*q+1] = fmaf(wv, bfhi(uu[q]), acc[2*q+1]);
      }
    }
  }
  float* dstp = zq + ((size_t)(b*256 + n))*256 + dc;
  float4 r0 = {acc[0], acc[1], acc[2], acc[3]};
  float4 r1 = {acc[4], acc[5], acc[6], acc[7]};
  *(float4*)dstp = r0;
  *(float4*)(dstp + 4) = r1;
}

// ---------------------------------------------------------------------------
extern "C" void kernel_launch(void* const* d_in, const int* in_sizes, int n_in,
                              void* d_out, int out_size, void* d_ws, size_t ws_size,
                              hipStream_t stream){
  (void)in_sizes; (void)n_in; (void)out_size; (void)ws_size;
  const float* ze    = (const float*)d_in[0];
  const float* cl    = (const float*)d_in[1];
  const float* books = (const float*)d_in[2];
  const float* lpq   = (const float*)d_in[3];
  const float* lpqc  = (const float*)d_in[4];
  float* out  = (float*)d_out;
  float* ws   = (float*)d_ws;
  float* zq   = out;
  float* prob = out + 2097153;
  float* logp = out + 2097153 + 4194304;

  uint16_t* bkrm = (uint16_t*)(ws + O_BKRM);
  uint16_t* bkTg = (uint16_t*)(ws + O_BKT);
  uint16_t* Mh   = (uint16_t*)(ws + O_MH);
  uint16_t* partp= (uint16_t*)(ws + O_PART);
  float*    lsegp= ws + F_LSE;

  k_prep<<<80, 256, 0, stream>>>(books, cl, lpq, lpqc, ws, out, bkrm, bkTg);
  k_mix<<<4096, 256, 0, stream>>>(bkrm, lpq, ws, Mh);
  k_probs_mf<<<256, 128, 0, stream>>>(ze, Mh, ws, lpq, prob, logp);
  k_zq_p<<<1280, 512, 0, stream>>>(ze, bkrm, bkTg, ws, lpq, partp, lsegp);
  k_comb<<<1024, 256, 0, stream>>>(partp, lsegp, ws, zq);
}